// Round 4
// baseline (1780.585 us; speedup 1.0000x reference)
//
#include <hip/hip_runtime.h>
#include <hip/hip_bf16.h>

typedef __attribute__((ext_vector_type(4))) float f32x4;
typedef __attribute__((ext_vector_type(8))) short short8;

// ---------- helpers ----------
static __device__ __forceinline__ unsigned short f2b(float f) {
    unsigned int x = __float_as_uint(f);
    return (unsigned short)((x + 0x7fffu + ((x >> 16) & 1u)) >> 16);
}
static __device__ __forceinline__ float sigm(float x) { return 1.0f / (1.0f + __expf(-x)); }
static __device__ __forceinline__ float tanh_fast(float x) { return 2.0f / (1.0f + __expf(-2.0f * x)) - 1.0f; }

// ---------- convert inputs to bf16 workspace ----------
__global__ void convert_kernel(const float* __restrict__ feats, const float* __restrict__ Wx,
                               const float* __restrict__ Wh, const float* __restrict__ Wp,
                               unsigned short* __restrict__ fb, unsigned short* __restrict__ wcat,
                               int nf4, int nw4) {
    int idx = blockIdx.x * blockDim.x + threadIdx.x;
    int stride = gridDim.x * blockDim.x;
    int tot = nf4 + nw4;
    for (int i = idx; i < tot; i += stride) {
        float4 v;
        unsigned short* dst;
        if (i < nf4) {
            v = ((const float4*)feats)[i];
            dst = fb + (size_t)i * 4;
        } else {
            int t = i - nf4;
            int row = t >> 8;
            int c4 = (t & 255) * 4;
            const float* src = nullptr;
            if (row < 2560) {
                src = (c4 < 512) ? (Wx + (size_t)row * 512 + c4)
                                 : (Wh + (size_t)row * 512 + (c4 - 512));
            } else {
                if (c4 < 512) src = Wp + (size_t)(row - 2560) * 512 + c4;
            }
            if (src) v = *(const float4*)src;
            else     v = make_float4(0.f, 0.f, 0.f, 0.f);
            dst = wcat + (size_t)row * 1024 + c4;
        }
        ushort4 o;
        o.x = f2b(v.x); o.y = f2b(v.y); o.z = f2b(v.z); o.w = f2b(v.w);
        *(ushort4*)dst = o;
    }
}

// ---------- fused level kernel: LDS-FREE, barrier-free ----------
// Block: 256 thr = 4 waves stacked on rows (128 rows); 16 output cols per block
// (grid.x = 32 col-slices -> fixed XCD per slice); 6 strips (i,o,f,u,r,px).
// Per wave: 32 rows x 16 cols x 6 strips -> acc 6x2xf32x4 = 48 VGPRs.
// All fragments loaded global->VGPR directly (16B/lane, coalesced); 2-deep
// named double-buffer; compiler inserts counted vmcnt (no LDS aliasing).
__global__ __launch_bounds__(256, 4)
void level_kernel(const unsigned short* __restrict__ fb,    // [N,512] bf16
                  const unsigned short* __restrict__ wcat,  // [3072,1024] bf16
                  unsigned short* __restrict__ hb,          // [N,512] bf16
                  const float* __restrict__ bx, const float* __restrict__ bh,
                  const float* __restrict__ bp,
                  float* __restrict__ c_all,                // [N,512] f32
                  float* __restrict__ out,                  // [N,512] f32
                  int s, int e, int level, int nks) {
    const int tid = threadIdx.x;
    const int lane = tid & 63;
    const int w = tid >> 6;
    const int q4 = lane >> 4;
    const int j0 = blockIdx.x * 16;
    const int nbase = s + blockIdx.y * 128 + w * 32;

    // per-lane base offsets (bf16-element units)
    unsigned aOff[2], hOff[2], bOff[6];
#pragma unroll
    for (int mi = 0; mi < 2; ++mi) {
        int n = nbase + mi * 16 + (lane & 15);
        if (n > e - 1) n = e - 1;
        aOff[mi] = (unsigned)n * 512u + q4 * 8;
        int pr = (n - 1) >> 3; if (pr < 0) pr = 0;
        hOff[mi] = (unsigned)pr * 512u + q4 * 8;
    }
#pragma unroll
    for (int g = 0; g < 6; ++g)
        bOff[g] = (unsigned)(g * 512 + j0 + (lane & 15)) * 1024u + q4 * 8;

    f32x4 acc[6][2];
#pragma unroll
    for (int g = 0; g < 6; ++g)
#pragma unroll
        for (int mi = 0; mi < 2; ++mi)
            acc[g][mi] = f32x4{0.f, 0.f, 0.f, 0.f};

    short8 A0[2], A1[2], B0[6], B1[6];

    // load fragment set for K-step ks
#define LOAD_SET(Ax, Bx, ks)                                                    \
    {                                                                           \
        const int _ks = (ks);                                                   \
        if (_ks < 16) {                                                         \
            _Pragma("unroll")                                                   \
            for (int mi = 0; mi < 2; ++mi)                                      \
                Ax[mi] = *(const short8*)(fb + aOff[mi] + _ks * 32);            \
        } else {                                                                \
            _Pragma("unroll")                                                   \
            for (int mi = 0; mi < 2; ++mi)                                      \
                Ax[mi] = *(const short8*)(hb + hOff[mi] + (_ks - 16) * 32);     \
        }                                                                       \
        _Pragma("unroll")                                                       \
        for (int g = 0; g < 6; ++g)                                             \
            if (g < 5 || _ks < 16)                                              \
                Bx[g] = *(const short8*)(wcat + bOff[g] + _ks * 32);            \
    }

#define MFMA_SET(Ax, Bx, ks)                                                    \
    {                                                                           \
        _Pragma("unroll")                                                       \
        for (int g = 0; g < 6; ++g) {                                           \
            if (g == 5 && (ks) >= 16) break;                                    \
            acc[g][0] = __builtin_amdgcn_mfma_f32_16x16x32_bf16(Ax[0], Bx[g], acc[g][0], 0, 0, 0); \
            acc[g][1] = __builtin_amdgcn_mfma_f32_16x16x32_bf16(Ax[1], Bx[g], acc[g][1], 0, 0, 0); \
        }                                                                       \
    }

    LOAD_SET(A0, B0, 0)
    for (int ks = 0; ks < nks; ks += 2) {
        LOAD_SET(A1, B1, ks + 1)
        MFMA_SET(A0, B0, ks)
        if (ks + 2 < nks) LOAD_SET(A0, B0, ks + 2)
        MFMA_SET(A1, B1, ks + 1)
    }
#undef LOAD_SET
#undef MFMA_SET

    // ---- epilogue: gates + highway. C/D layout: col=lane&15, row=q4*4+q
    const int j = j0 + (lane & 15);
    const float Bi = bx[j]        + bh[j];
    const float Bo = bx[j + 512]  + bh[j + 512];
    const float Bf = bx[j + 1024] + bh[j + 1024];
    const float Bu = bx[j + 1536] + bh[j + 1536];
    const float Br = bx[j + 2048] + bh[j + 2048];
    const float Bp = bp[j];
#pragma unroll
    for (int mi = 0; mi < 2; ++mi) {
        const int rowb = mi * 16 + (q4 << 2);
#pragma unroll
        for (int q = 0; q < 4; ++q) {
            int n = nbase + rowb + q;
            if (n >= e) continue;
            float gi = sigm(acc[0][mi][q] + Bi);
            float go = sigm(acc[1][mi][q] + Bo);
            float gf = sigm(acc[2][mi][q] + Bf);
            float gu = tanh_fast(acc[3][mi][q] + Bu);
            float gr = sigm(acc[4][mi][q] + Br);
            float pp = acc[5][mi][q] + Bp;
            float pc = (level > 0) ? c_all[(size_t)((n - 1) >> 3) * 512 + j] : 0.0f;
            float cg = gi * gu + gf * pc;
            float hh = go * tanh_fast(cg);
            float hf = gr * hh + (1.0f - gr) * pp;
            size_t o = (size_t)n * 512 + j;
            c_all[o] = cg;
            out[o] = hf;
            hb[o] = f2b(hf);
        }
    }
}

// ---------- host ----------
extern "C" void kernel_launch(void* const* d_in, const int* in_sizes, int n_in,
                              void* d_out, int out_size, void* d_ws, size_t ws_size,
                              hipStream_t stream) {
    const float* feats = (const float*)d_in[0];
    const float* Wx = (const float*)d_in[1];
    const float* bx = (const float*)d_in[2];
    const float* Wh = (const float*)d_in[3];
    const float* bh = (const float*)d_in[4];
    const float* Wp = (const float*)d_in[5];
    const float* bp = (const float*)d_in[6];
    float* out = (float*)d_out;

    const int N = in_sizes[0] / 512;

    unsigned short* fb = (unsigned short*)d_ws;                 // N*512 bf16
    unsigned short* wcat = fb + (size_t)N * 512;                // 3072*1024 bf16
    unsigned short* hb = wcat + (size_t)3072 * 1024;            // N*512 bf16
    float* c_all = (float*)(hb + (size_t)N * 512);              // N*512 f32

    const int nf4 = N * 512 / 4;
    const int nw4 = 3072 * 1024 / 4;
    convert_kernel<<<dim3(2048), dim3(256), 0, stream>>>(feats, Wx, Wh, Wp, fb, wcat, nf4, nw4);

    int bounds[16];
    bounds[0] = 0;
    long cnt = 1;
    int nl = 0;
    while (bounds[nl] < N) {
        long nxt = (long)bounds[nl] + cnt;
        if (nxt > N) nxt = N;
        bounds[nl + 1] = (int)nxt;
        nl++;
        cnt *= 8;
    }

    for (int l = 0; l < nl; ++l) {
        int s = bounds[l], e = bounds[l + 1];
        int rows = e - s;
        int nks = (l > 0) ? 32 : 16;
        dim3 grid(32, (rows + 127) / 128);
        level_kernel<<<grid, dim3(256), 0, stream>>>(fb, wcat, hb, bx, bh, bp, c_all, out, s, e, l, nks);
    }
}